// Round 1
// baseline (4046.692 us; speedup 1.0000x reference)
//
#include <hip/hip_runtime.h>
#include <hip/hip_bf16.h>

#define REC_NWG 32   // workgroups per direction

__device__ __forceinline__ float sigm_(float x) { return 1.f / (1.f + __expf(-x)); }
__device__ __forceinline__ float tanh_(float x) { return 1.f - 2.f / (__expf(2.f * x) + 1.f); }

// ---------------- embedding concat: x[t] = [word_emb[wi[t]], pos_emb[pi[t]]] ----------------
__global__ void embed_kernel(const int* __restrict__ wi, const int* __restrict__ pi,
                             const float* __restrict__ we, const float* __restrict__ pe,
                             float* __restrict__ x) {
    int t = blockIdx.x;
    int w = wi[t], p = pi[t];
    for (int c = threadIdx.x; c < 400; c += 128) {
        x[t * 400 + c] = (c < 300) ? we[(size_t)w * 300 + c] : pe[(size_t)p * 100 + (c - 300)];
    }
}

// ---------------- generic C[M][N] = X[M][K] @ W[N][K]^T + bias, batched over z ----------------
// tiles: 64x64, BK=16, 256 threads, 4x4 micro-tile per thread
__global__ __launch_bounds__(256) void gemm_xwt(
    const float* __restrict__ X, int ldx,
    const float* __restrict__ W, int ldw, size_t wbs,
    const float* __restrict__ b1, const float* __restrict__ b2, int bbs,
    float* __restrict__ C, int ldc, size_t cbs, int K) {
    int z = blockIdx.z;
    const float* Wz = W + (size_t)z * wbs;
    float* Cz = C + (size_t)z * cbs;
    int n0 = blockIdx.x * 64, m0 = blockIdx.y * 64;
    int tid = threadIdx.x;
    __shared__ __align__(16) float Xs[16][68];
    __shared__ __align__(16) float Ws[16][68];
    int lr = tid >> 2;            // 0..63 tile row
    int lk = (tid & 3) * 4;       // k offset (4 floats)
    int ty = tid >> 4, tx = tid & 15;
    float acc[4][4] = {{0.f}};
    const float* Xp = X + (size_t)(m0 + lr) * ldx + lk;
    const float* Wp = Wz + (size_t)(n0 + lr) * ldw + lk;
    for (int k0 = 0; k0 < K; k0 += 16) {
        float4 xv = *(const float4*)(Xp + k0);
        float4 wv = *(const float4*)(Wp + k0);
        __syncthreads();
        Xs[lk + 0][lr] = xv.x; Xs[lk + 1][lr] = xv.y; Xs[lk + 2][lr] = xv.z; Xs[lk + 3][lr] = xv.w;
        Ws[lk + 0][lr] = wv.x; Ws[lk + 1][lr] = wv.y; Ws[lk + 2][lr] = wv.z; Ws[lk + 3][lr] = wv.w;
        __syncthreads();
#pragma unroll
        for (int kk = 0; kk < 16; ++kk) {
            float4 a = *(const float4*)&Xs[kk][ty * 4];
            float4 b = *(const float4*)&Ws[kk][tx * 4];
            acc[0][0] += a.x * b.x; acc[0][1] += a.x * b.y; acc[0][2] += a.x * b.z; acc[0][3] += a.x * b.w;
            acc[1][0] += a.y * b.x; acc[1][1] += a.y * b.y; acc[1][2] += a.y * b.z; acc[1][3] += a.y * b.w;
            acc[2][0] += a.z * b.x; acc[2][1] += a.z * b.y; acc[2][2] += a.z * b.z; acc[2][3] += a.z * b.w;
            acc[3][0] += a.w * b.x; acc[3][1] += a.w * b.y; acc[3][2] += a.w * b.z; acc[3][3] += a.w * b.w;
        }
    }
#pragma unroll
    for (int i = 0; i < 4; ++i) {
        int m = m0 + ty * 4 + i;
#pragma unroll
        for (int j = 0; j < 4; ++j) {
            int n = n0 + tx * 4 + j;
            float bv = 0.f;
            if (b1) bv += b1[z * bbs + n];
            if (b2) bv += b2[z * bbs + n];
            Cz[(size_t)m * ldc + n] = acc[i][j] + bv;
        }
    }
}

// ---------------- LSTM recurrence: 2 directions x REC_NWG WGs, flag-synced per step ----------------
// xg:   [2][512][2048] precomputed input gates (+bias)
// w_hh: [2][2048][512]
// hs:   [512][1024]  (cols 0..511 fwd, 512..1023 bwd)
// flags:[2][512] step counters (must be zeroed before launch)
__global__ __launch_bounds__(256, 1) void lstm_rec(
    const float* __restrict__ xg, const float* __restrict__ w_hh,
    float* __restrict__ hs, int* __restrict__ flags) {
    int bid = blockIdx.x;
    int d = bid >> 5;     // direction
    int k = bid & 31;     // h-chunk (16 elems)
    int tid = threadIdx.x;
    int r = tid >> 2;     // 0..63 local gate row
    int q = tid & 3;      // column quarter (128 cols each)
    int j_local = r >> 2; // 0..15
    int gate = r & 3;     // 0=i,1=f,2=g,3=o
    int grow = gate * 512 + k * 16 + j_local; // row in w_hh / col in xg

    // weights stationary in registers: 128 floats (statically indexed via unroll)
    const float* wrow = w_hh + (size_t)d * 2048 * 512 + (size_t)grow * 512 + q * 128;
    float w[128];
#pragma unroll
    for (int i = 0; i < 32; ++i) {
        float4 v = ((const float4*)wrow)[i];
        w[4 * i + 0] = v.x; w[4 * i + 1] = v.y; w[4 * i + 2] = v.z; w[4 * i + 3] = v.w;
    }
    const float* xgd = xg + (size_t)d * 512 * 2048;
    int* cnt = flags + d * 512;

    __shared__ float4 h4[128];     // swizzled h_prev
    __shared__ float gate_lds[64];
    float c = 0.f;

    for (int ti = 0; ti < 512; ++ti) {
        int t = d ? (511 - ti) : ti;
        float a0 = 0.f, a1 = 0.f, a2 = 0.f, a3 = 0.f;
        if (ti > 0) {
            int tp = d ? (t + 1) : (t - 1);
            if (tid == 0) {
                while (__hip_atomic_load(&cnt[ti - 1], __ATOMIC_ACQUIRE, __HIP_MEMORY_SCOPE_AGENT) < REC_NWG) {
                    __builtin_amdgcn_s_sleep(8);
                }
            }
            __syncthreads();
            if (tid < 128) {
                float4 v = ((const float4*)(hs + (size_t)tp * 1024 + d * 512))[tid];
                h4[tid ^ (tid >> 5)] = v;   // quad-swizzle to spread banks
            }
            __syncthreads();
#pragma unroll
            for (int i = 0; i < 32; ++i) {
                float4 hv = h4[(q * 32 + i) ^ q];
                a0 += w[4 * i + 0] * hv.x;
                a1 += w[4 * i + 1] * hv.y;
                a2 += w[4 * i + 2] * hv.z;
                a3 += w[4 * i + 3] * hv.w;
            }
        }
        float acc = (a0 + a1) + (a2 + a3);
        acc += __shfl_xor(acc, 1);
        acc += __shfl_xor(acc, 2);
        if (q == 0) gate_lds[r] = acc + xgd[(size_t)t * 2048 + grow];
        __syncthreads();
        if (tid < 16) {
            float gi = gate_lds[4 * tid + 0];
            float gf = gate_lds[4 * tid + 1];
            float gg = gate_lds[4 * tid + 2];
            float go = gate_lds[4 * tid + 3];
            float iv = sigm_(gi), fv = sigm_(gf), gv = tanh_(gg), ov = sigm_(go);
            c = fv * c + iv * gv;
            float h = ov * tanh_(c);
            hs[(size_t)t * 1024 + d * 512 + k * 16 + tid] = h;
        }
        __syncthreads();  // drains vmcnt: h stores are in L2 before the flag
        if (tid == 0) {
            __hip_atomic_fetch_add(&cnt[ti], 1, __ATOMIC_RELEASE, __HIP_MEMORY_SCOPE_AGENT);
        }
    }
}

// ---------------- scorer: scores[i][j] = sum_m W2[m]*tanh(Xh[i][m]+Ym[j][m])  (b1 folded into Xh, b2 cancels in log_softmax) ----------------
__global__ __launch_bounds__(256) void scorer(const float* __restrict__ Xh, const float* __restrict__ Ym,
                                              const float* __restrict__ W2, float* __restrict__ sc) {
    int i0 = blockIdx.y * 16, j0 = blockIdx.x * 16;
    int tid = threadIdx.x;
    __shared__ float xs[512][16];  // [m][local-i]
    __shared__ float ys[512][16];  // [m][local-j]
    __shared__ float w2s[512];
    {
        int rr = tid >> 4, cc = (tid & 15) * 32;
        const float4* xg4 = (const float4*)(Xh + (size_t)(i0 + rr) * 512 + cc);
        const float4* yg4 = (const float4*)(Ym + (size_t)(j0 + rr) * 512 + cc);
#pragma unroll
        for (int u = 0; u < 8; ++u) {
            float4 a = xg4[u];
            float4 b = yg4[u];
            int mb = cc + u * 4;
            xs[mb + 0][rr] = a.x; xs[mb + 1][rr] = a.y; xs[mb + 2][rr] = a.z; xs[mb + 3][rr] = a.w;
            ys[mb + 0][rr] = b.x; ys[mb + 1][rr] = b.y; ys[mb + 2][rr] = b.z; ys[mb + 3][rr] = b.w;
        }
        for (int m = tid; m < 512; m += 256) w2s[m] = W2[m];
    }
    __syncthreads();
    int ii = tid >> 4, jj = tid & 15;
    float acc = 0.f;
#pragma unroll 4
    for (int m = 0; m < 512; ++m) {
        float v = xs[m][ii] + ys[m][jj];
        acc += w2s[m] * (1.f - 2.f / (__expf(2.f * v) + 1.f));
    }
    sc[(size_t)(i0 + ii) * 512 + (j0 + jj)] = acc;
}

// ---------------- per-column log-sum-exp + gather picked score ----------------
__global__ __launch_bounds__(256) void col_lse(const float* __restrict__ sc, const int* __restrict__ heads,
                                               float* __restrict__ part) {
    int j = blockIdx.x;
    int tid = threadIdx.x;
    float v1 = sc[(size_t)tid * 512 + j];
    float v2 = sc[(size_t)(tid + 256) * 512 + j];
    float m = fmaxf(v1, v2);
    for (int o = 1; o < 64; o <<= 1) m = fmaxf(m, __shfl_xor(m, o));
    __shared__ float red[4], red2[4];
    if ((tid & 63) == 0) red[tid >> 6] = m;
    __syncthreads();
    m = fmaxf(fmaxf(red[0], red[1]), fmaxf(red[2], red[3]));
    float s = __expf(v1 - m) + __expf(v2 - m);
    for (int o = 1; o < 64; o <<= 1) s += __shfl_xor(s, o);
    if ((tid & 63) == 0) red2[tid >> 6] = s;
    __syncthreads();
    if (tid == 0) {
        s = red2[0] + red2[1] + red2[2] + red2[3];
        part[j] = sc[(size_t)heads[j] * 512 + j] - (m + logf(s));
    }
}

__global__ void final_red(const float* __restrict__ part, float* __restrict__ out) {
    int tid = threadIdx.x; // 512
    float v = part[tid];
    for (int o = 1; o < 64; o <<= 1) v += __shfl_xor(v, o);
    __shared__ float red[8];
    if ((tid & 63) == 0) red[tid >> 6] = v;
    __syncthreads();
    if (tid == 0) {
        float s = 0.f;
        for (int i = 0; i < 8; ++i) s += red[i];
        out[0] = -s / 512.f;
    }
}

extern "C" void kernel_launch(void* const* d_in, const int* in_sizes, int n_in,
                              void* d_out, int out_size, void* d_ws, size_t ws_size,
                              hipStream_t stream) {
    const int* word_idx = (const int*)d_in[0];
    const int* pos_idx  = (const int*)d_in[1];
    const int* heads    = (const int*)d_in[2];
    const float* we     = (const float*)d_in[3];
    const float* pe     = (const float*)d_in[4];
    const float* w_ih0  = (const float*)d_in[5];
    const float* w_hh0  = (const float*)d_in[6];
    const float* b_ih0  = (const float*)d_in[7];
    const float* b_hh0  = (const float*)d_in[8];
    const float* w_ih1  = (const float*)d_in[9];
    const float* w_hh1  = (const float*)d_in[10];
    const float* b_ih1  = (const float*)d_in[11];
    const float* b_hh1  = (const float*)d_in[12];
    const float* W1     = (const float*)d_in[13];
    const float* b1v    = (const float*)d_in[14];
    const float* W2     = (const float*)d_in[15];
    float* out = (float*)d_out;

    float* ws  = (float*)d_ws;                 // ~25 MB total
    float* x_  = ws;                           // 512*400
    float* xg0 = x_  + 204800;                 // 2*512*2048
    float* hs0 = xg0 + 2097152;                // 512*1024 (concat layout)
    float* xg1 = hs0 + 524288;                 // 2*512*2048
    float* hs1 = xg1 + 2097152;                // 512*1024
    float* Xh  = hs1 + 524288;                 // 512*512
    float* Ym  = Xh  + 262144;                 // 512*512
    float* scb = Ym  + 262144;                 // 512*512
    float* part= scb + 262144;                 // 512
    int*  flg  = (int*)(part + 512);           // 2 layers * 2 dirs * 512

    hipMemsetAsync(flg, 0, 2048 * sizeof(int), stream);

    embed_kernel<<<512, 128, 0, stream>>>(word_idx, pos_idx, we, pe, x_);

    // layer 0 input gates: (512x400)@(400x2048)^T + (b_ih0+b_hh0), per direction
    gemm_xwt<<<dim3(32, 8, 2), 256, 0, stream>>>(x_, 400, w_ih0, 400, (size_t)2048 * 400,
                                                 b_ih0, b_hh0, 2048, xg0, 2048, (size_t)512 * 2048, 400);
    lstm_rec<<<64, 256, 0, stream>>>(xg0, w_hh0, hs0, flg);

    // layer 1 input gates: (512x1024)@(1024x2048)^T + (b_ih1+b_hh1)
    gemm_xwt<<<dim3(32, 8, 2), 256, 0, stream>>>(hs0, 1024, w_ih1, 1024, (size_t)2048 * 1024,
                                                 b_ih1, b_hh1, 2048, xg1, 2048, (size_t)512 * 2048, 1024);
    lstm_rec<<<64, 256, 0, stream>>>(xg1, w_hh1, hs1, flg + 1024);

    // MLP projections: Xh = h@A^T + b1 ; Ym = h@B^T   (A=W1[:, :1024], B=W1[:, 1024:])
    gemm_xwt<<<dim3(8, 8, 1), 256, 0, stream>>>(hs1, 1024, W1, 2048, 0,
                                                b1v, nullptr, 0, Xh, 512, 0, 1024);
    gemm_xwt<<<dim3(8, 8, 1), 256, 0, stream>>>(hs1, 1024, W1 + 1024, 2048, 0,
                                                nullptr, nullptr, 0, Ym, 512, 0, 1024);

    scorer<<<dim3(32, 32), 256, 0, stream>>>(Xh, Ym, W2, scb);
    col_lse<<<512, 256, 0, stream>>>(scb, heads, part);
    final_red<<<1, 512, 0, stream>>>(part, out);
}

// Round 2
// 3978.103 us; speedup vs baseline: 1.0172x; 1.0172x over previous
//
#include <hip/hip_runtime.h>
#include <hip/hip_bf16.h>

#define RWG 16   // workgroups per direction

__device__ __forceinline__ float sigm_(float x) { return 1.f / (1.f + __expf(-x)); }
__device__ __forceinline__ float tanh_(float x) { return 1.f - 2.f / (__expf(2.f * x) + 1.f); }

// ---------------- embedding concat: x[t] = [word_emb[wi[t]], pos_emb[pi[t]]] ----------------
__global__ void embed_kernel(const int* __restrict__ wi, const int* __restrict__ pi,
                             const float* __restrict__ we, const float* __restrict__ pe,
                             float* __restrict__ x) {
    int t = blockIdx.x;
    int w = wi[t], p = pi[t];
    for (int c = threadIdx.x; c < 400; c += 128) {
        x[t * 400 + c] = (c < 300) ? we[(size_t)w * 300 + c] : pe[(size_t)p * 100 + (c - 300)];
    }
}

// ---------------- generic C[M][N] = X[M][K] @ W[N][K]^T + bias, batched over z ----------------
__global__ __launch_bounds__(256) void gemm_xwt(
    const float* __restrict__ X, int ldx,
    const float* __restrict__ W, int ldw, size_t wbs,
    const float* __restrict__ b1, const float* __restrict__ b2, int bbs,
    float* __restrict__ C, int ldc, size_t cbs, int K) {
    int z = blockIdx.z;
    const float* Wz = W + (size_t)z * wbs;
    float* Cz = C + (size_t)z * cbs;
    int n0 = blockIdx.x * 64, m0 = blockIdx.y * 64;
    int tid = threadIdx.x;
    __shared__ __align__(16) float Xs[16][68];
    __shared__ __align__(16) float Ws[16][68];
    int lr = tid >> 2;
    int lk = (tid & 3) * 4;
    int ty = tid >> 4, tx = tid & 15;
    float acc[4][4] = {{0.f}};
    const float* Xp = X + (size_t)(m0 + lr) * ldx + lk;
    const float* Wp = Wz + (size_t)(n0 + lr) * ldw + lk;
    for (int k0 = 0; k0 < K; k0 += 16) {
        float4 xv = *(const float4*)(Xp + k0);
        float4 wv = *(const float4*)(Wp + k0);
        __syncthreads();
        Xs[lk + 0][lr] = xv.x; Xs[lk + 1][lr] = xv.y; Xs[lk + 2][lr] = xv.z; Xs[lk + 3][lr] = xv.w;
        Ws[lk + 0][lr] = wv.x; Ws[lk + 1][lr] = wv.y; Ws[lk + 2][lr] = wv.z; Ws[lk + 3][lr] = wv.w;
        __syncthreads();
#pragma unroll
        for (int kk = 0; kk < 16; ++kk) {
            float4 a = *(const float4*)&Xs[kk][ty * 4];
            float4 b = *(const float4*)&Ws[kk][tx * 4];
            acc[0][0] += a.x * b.x; acc[0][1] += a.x * b.y; acc[0][2] += a.x * b.z; acc[0][3] += a.x * b.w;
            acc[1][0] += a.y * b.x; acc[1][1] += a.y * b.y; acc[1][2] += a.y * b.z; acc[1][3] += a.y * b.w;
            acc[2][0] += a.z * b.x; acc[2][1] += a.z * b.y; acc[2][2] += a.z * b.z; acc[2][3] += a.z * b.w;
            acc[3][0] += a.w * b.x; acc[3][1] += a.w * b.y; acc[3][2] += a.w * b.z; acc[3][3] += a.w * b.w;
        }
    }
#pragma unroll
    for (int i = 0; i < 4; ++i) {
        int m = m0 + ty * 4 + i;
#pragma unroll
        for (int j = 0; j < 4; ++j) {
            int n = n0 + tx * 4 + j;
            float bv = 0.f;
            if (b1) bv += b1[z * bbs + n];
            if (b2) bv += b2[z * bbs + n];
            Cz[(size_t)m * ldc + n] = acc[i][j] + bv;
        }
    }
}

// ---------------- LSTM recurrence: 2 dirs x RWG WGs of 512 threads, seq-word sync ----------------
// xg:   [2][512][2048] precomputed input gates (+bias)
// w_hh: [2][2048][512]
// hs:   [512][1024]  (cols 0..511 fwd, 512..1023 bwd)
// seqs: [2][RWG] step stamps (zeroed before launch); writer sets seq[k]=ti+1 after step ti's h is agent-visible
__global__ __launch_bounds__(512, 2) void lstm_rec(
    const float* __restrict__ xg, const float* __restrict__ w_hh,
    float* __restrict__ hs, int* __restrict__ seqs) {
    int bid = blockIdx.x;
    int d = bid >> 4;     // direction
    int k = bid & 15;     // h-chunk (32 elems)
    int tid = threadIdx.x;
    int r = tid >> 2;     // 0..127 local gate row
    int q = tid & 3;      // column quarter (128 cols)
    int j_local = r >> 2; // 0..31
    int gate = r & 3;     // 0=i,1=f,2=g,3=o
    int grow = gate * 512 + k * 32 + j_local;

    // stationary weights: 128 floats/thread, statically indexed
    const float* wrow = w_hh + (size_t)d * (2048 * 512) + (size_t)grow * 512 + q * 128;
    float w[128];
#pragma unroll
    for (int i = 0; i < 32; ++i) {
        float4 v = ((const float4*)wrow)[i];
        w[4 * i + 0] = v.x; w[4 * i + 1] = v.y; w[4 * i + 2] = v.z; w[4 * i + 3] = v.w;
    }
    const float* xgd = xg + (size_t)d * (512 * 2048);
    int* sq = seqs + d * RWG;

    __shared__ float4 h4[128];      // swizzled h_prev
    __shared__ float gate_lds[128];
    float c = 0.f;

    for (int ti = 0; ti < 512; ++ti) {
        int t = d ? (511 - ti) : ti;
        // prefetch xg for this step (independent of h) — hides under the spin
        float xgv = 0.f;
        if (q == 0) xgv = xgd[(size_t)t * 2048 + grow];

        float a0 = 0.f, a1 = 0.f, a2 = 0.f, a3 = 0.f;
        if (ti > 0) {
            int tp = d ? (t + 1) : (t - 1);
            if (tid < 64) {
                // wave 0: 16 lanes poll 16 seq words in parallel
                while (true) {
                    int v = ti;
                    if (tid < RWG) v = __hip_atomic_load(&sq[tid], __ATOMIC_ACQUIRE, __HIP_MEMORY_SCOPE_AGENT);
                    if (__all(v >= ti)) break;
                    __builtin_amdgcn_s_sleep(1);
                }
                __builtin_amdgcn_fence(__ATOMIC_ACQUIRE, "agent");
                // wave 0 loads h_prev immediately (512 floats = 64 lanes x 2 float4)
                const float4* hp = (const float4*)(hs + (size_t)tp * 1024 + d * 512);
                float4 v0 = hp[tid];
                float4 v1 = hp[tid + 64];
                h4[tid ^ (tid >> 5)] = v0;
                h4[(tid + 64) ^ ((tid + 64) >> 5)] = v1;
            }
            __syncthreads();   // barrier 1: h4 ready
#pragma unroll
            for (int i = 0; i < 32; ++i) {
                float4 hv = h4[(q * 32 + i) ^ q];
                a0 += w[4 * i + 0] * hv.x;
                a1 += w[4 * i + 1] * hv.y;
                a2 += w[4 * i + 2] * hv.z;
                a3 += w[4 * i + 3] * hv.w;
            }
        }
        float acc = (a0 + a1) + (a2 + a3);
        acc += __shfl_xor(acc, 1);
        acc += __shfl_xor(acc, 2);
        if (q == 0) gate_lds[r] = acc + xgv;
        __syncthreads();   // barrier 2: gates ready (also protects h4/gate_lds reuse across steps)
        if (tid < 32) {
            float gi = gate_lds[4 * tid + 0];
            float gf = gate_lds[4 * tid + 1];
            float gg = gate_lds[4 * tid + 2];
            float go = gate_lds[4 * tid + 3];
            float iv = sigm_(gi), fv = sigm_(gf), gv = tanh_(gg), ov = sigm_(go);
            c = fv * c + iv * gv;
            float h = ov * tanh_(c);
            hs[(size_t)t * 1024 + d * 512 + k * 32 + tid] = h;
        }
        // h stores and seq store are both wave 0: per-wave vmcnt ordering + release fence suffice
        if (tid == 0) {
            __hip_atomic_store(&sq[k], ti + 1, __ATOMIC_RELEASE, __HIP_MEMORY_SCOPE_AGENT);
        }
    }
}

// ---------------- scorer: scores[i][j] = sum_m W2[m]*tanh(Xh[i][m]+Ym[j][m]) ----------------
__global__ __launch_bounds__(256) void scorer(const float* __restrict__ Xh, const float* __restrict__ Ym,
                                              const float* __restrict__ W2, float* __restrict__ sc) {
    int i0 = blockIdx.y * 16, j0 = blockIdx.x * 16;
    int tid = threadIdx.x;
    __shared__ float xs[512][16];
    __shared__ float ys[512][16];
    __shared__ float w2s[512];
    {
        int rr = tid >> 4, cc = (tid & 15) * 32;
        const float4* xg4 = (const float4*)(Xh + (size_t)(i0 + rr) * 512 + cc);
        const float4* yg4 = (const float4*)(Ym + (size_t)(j0 + rr) * 512 + cc);
#pragma unroll
        for (int u = 0; u < 8; ++u) {
            float4 a = xg4[u];
            float4 b = yg4[u];
            int mb = cc + u * 4;
            xs[mb + 0][rr] = a.x; xs[mb + 1][rr] = a.y; xs[mb + 2][rr] = a.z; xs[mb + 3][rr] = a.w;
            ys[mb + 0][rr] = b.x; ys[mb + 1][rr] = b.y; ys[mb + 2][rr] = b.z; ys[mb + 3][rr] = b.w;
        }
        for (int m = tid; m < 512; m += 256) w2s[m] = W2[m];
    }
    __syncthreads();
    int ii = tid >> 4, jj = tid & 15;
    float acc = 0.f;
#pragma unroll 4
    for (int m = 0; m < 512; ++m) {
        float v = xs[m][ii] + ys[m][jj];
        acc += w2s[m] * (1.f - 2.f / (__expf(2.f * v) + 1.f));
    }
    sc[(size_t)(i0 + ii) * 512 + (j0 + jj)] = acc;
}

// ---------------- per-column log-sum-exp + gather picked score ----------------
__global__ __launch_bounds__(256) void col_lse(const float* __restrict__ sc, const int* __restrict__ heads,
                                               float* __restrict__ part) {
    int j = blockIdx.x;
    int tid = threadIdx.x;
    float v1 = sc[(size_t)tid * 512 + j];
    float v2 = sc[(size_t)(tid + 256) * 512 + j];
    float m = fmaxf(v1, v2);
    for (int o = 1; o < 64; o <<= 1) m = fmaxf(m, __shfl_xor(m, o));
    __shared__ float red[4], red2[4];
    if ((tid & 63) == 0) red[tid >> 6] = m;
    __syncthreads();
    m = fmaxf(fmaxf(red[0], red[1]), fmaxf(red[2], red[3]));
    float s = __expf(v1 - m) + __expf(v2 - m);
    for (int o = 1; o < 64; o <<= 1) s += __shfl_xor(s, o);
    if ((tid & 63) == 0) red2[tid >> 6] = s;
    __syncthreads();
    if (tid == 0) {
        s = red2[0] + red2[1] + red2[2] + red2[3];
        part[j] = sc[(size_t)heads[j] * 512 + j] - (m + logf(s));
    }
}

__global__ void final_red(const float* __restrict__ part, float* __restrict__ out) {
    int tid = threadIdx.x; // 512
    float v = part[tid];
    for (int o = 1; o < 64; o <<= 1) v += __shfl_xor(v, o);
    __shared__ float red[8];
    if ((tid & 63) == 0) red[tid >> 6] = v;
    __syncthreads();
    if (tid == 0) {
        float s = 0.f;
        for (int i = 0; i < 8; ++i) s += red[i];
        out[0] = -s / 512.f;
    }
}

extern "C" void kernel_launch(void* const* d_in, const int* in_sizes, int n_in,
                              void* d_out, int out_size, void* d_ws, size_t ws_size,
                              hipStream_t stream) {
    const int* word_idx = (const int*)d_in[0];
    const int* pos_idx  = (const int*)d_in[1];
    const int* heads    = (const int*)d_in[2];
    const float* we     = (const float*)d_in[3];
    const float* pe     = (const float*)d_in[4];
    const float* w_ih0  = (const float*)d_in[5];
    const float* w_hh0  = (const float*)d_in[6];
    const float* b_ih0  = (const float*)d_in[7];
    const float* b_hh0  = (const float*)d_in[8];
    const float* w_ih1  = (const float*)d_in[9];
    const float* w_hh1  = (const float*)d_in[10];
    const float* b_ih1  = (const float*)d_in[11];
    const float* b_hh1  = (const float*)d_in[12];
    const float* W1     = (const float*)d_in[13];
    const float* b1v    = (const float*)d_in[14];
    const float* W2     = (const float*)d_in[15];
    float* out = (float*)d_out;

    float* ws  = (float*)d_ws;
    float* x_  = ws;                           // 512*400
    float* xg0 = x_  + 204800;                 // 2*512*2048
    float* hs0 = xg0 + 2097152;                // 512*1024
    float* xg1 = hs0 + 524288;                 // 2*512*2048
    float* hs1 = xg1 + 2097152;                // 512*1024
    float* Xh  = hs1 + 524288;                 // 512*512
    float* Ym  = Xh  + 262144;                 // 512*512
    float* scb = Ym  + 262144;                 // 512*512
    float* part= scb + 262144;                 // 512
    int*  flg  = (int*)(part + 512);           // seq words

    hipMemsetAsync(flg, 0, 256 * sizeof(int), stream);

    embed_kernel<<<512, 128, 0, stream>>>(word_idx, pos_idx, we, pe, x_);

    gemm_xwt<<<dim3(32, 8, 2), 256, 0, stream>>>(x_, 400, w_ih0, 400, (size_t)2048 * 400,
                                                 b_ih0, b_hh0, 2048, xg0, 2048, (size_t)512 * 2048, 400);
    lstm_rec<<<32, 512, 0, stream>>>(xg0, w_hh0, hs0, flg);

    gemm_xwt<<<dim3(32, 8, 2), 256, 0, stream>>>(hs0, 1024, w_ih1, 1024, (size_t)2048 * 1024,
                                                 b_ih1, b_hh1, 2048, xg1, 2048, (size_t)512 * 2048, 1024);
    lstm_rec<<<32, 512, 0, stream>>>(xg1, w_hh1, hs1, flg + 32);

    gemm_xwt<<<dim3(8, 8, 1), 256, 0, stream>>>(hs1, 1024, W1, 2048, 0,
                                                b1v, nullptr, 0, Xh, 512, 0, 1024);
    gemm_xwt<<<dim3(8, 8, 1), 256, 0, stream>>>(hs1, 1024, W1 + 1024, 2048, 0,
                                                nullptr, nullptr, 0, Ym, 512, 0, 1024);

    scorer<<<dim3(32, 32), 256, 0, stream>>>(Xh, Ym, W2, scb);
    col_lse<<<512, 256, 0, stream>>>(scb, heads, part);
    final_red<<<1, 512, 0, stream>>>(part, out);
}